// Round 2
// baseline (193.968 us; speedup 1.0000x reference)
//
#include <hip/hip_runtime.h>
#include <hip/hip_bf16.h>

#define D 64            // D_IN == D_OUT == 64
#define K 24            // slots/node; deg~Poisson(10): P(>24)~3e-5 -> ~10 spill edges (inline, exact)
#define M44 ((1ULL << 44) - 1)
#define SPILLCAP 65536

typedef __attribute__((ext_vector_type(4))) _Float16 half4;
typedef __attribute__((ext_vector_type(8))) _Float16 half8;

// ---------------------------------------------------------------------------
// k_build v2 (r1-PROVEN): XCD-AFFINE row-parity partition.
// r0->r1: WRITE_SIZE 61MB->(build off top-5), build 78us -> <66us, total -18us.
// 8x blocks; block b handles edge chunk b>>3 filtered to rows (r&7)==(b&7):
// exact partition, and blockIdx round-robin puts each row's slot lines on ONE
// XCD L2 -> single dirty copy -> writebacks no longer fight the atomics.
// MEASURED WALLS: ~21.5G RMW/s device atomics; 1 edge/thread (r10); separate
// dispatches (r12).
__global__ __launch_bounds__(256) void k_build(const int* __restrict__ rowi,
                                               const int* __restrict__ coli,
                                               const float* __restrict__ ew,
                                               unsigned long long* __restrict__ packed,
                                               unsigned int* __restrict__ slots,
                                               int4* __restrict__ spill,
                                               int* __restrict__ spillCnt, int nE) {
    int b = blockIdx.x;
    int p = b & 7;                      // parity class this block serves
    int e = (b >> 3) * 256 + threadIdx.x;
    if (e >= nE) return;
    int r = rowi[e];
    if ((r & 7) != p) return;           // another block (on the right XCD) owns it
    int c = coli[e];
    float w = ew[e];
    unsigned long long fx = (unsigned long long)((double)w * 4294967296.0);
    unsigned long long old = atomicAdd(&packed[r], (1ULL << 44) | fx);
    int rank = (int)(old >> 44);
    if (rank < K) {
        int q = (int)(w * 32768.0f + 0.5f);
        if (q > 32767) q = 32767;
        slots[r * K + rank] = ((unsigned int)c << 15) | (unsigned int)q;
    } else {
        int pI = atomicAdd(spillCnt, 1);
        if (pI < SPILLCAP) spill[pI] = make_int4(r, c, __float_as_int(w), 0);
    }
}

// k_xhalf: x fp32 -> fp16 pre-pass (r1). The gather reads x 259MB logically
// (1M random 256B rows); fp16 halves that AND fits 12.8MB vs 25.6MB in the
// per-XCD L2s. Streaming, ~6us. Error: 2^-11 rel on x -> ~2e-4 on out,
// invisible next to the 0.0078 q15-weight absmax.
__global__ __launch_bounds__(256) void k_xhalf(const float4* __restrict__ x4,
                                               half8* __restrict__ xh8, int nv) {
    int t = blockIdx.x * 256 + threadIdx.x;
    if (t >= nv) return;
    float4 a = x4[2 * t], b = x4[2 * t + 1];
    half8 h;
    h[0] = (_Float16)a.x; h[1] = (_Float16)a.y; h[2] = (_Float16)a.z; h[3] = (_Float16)a.w;
    h[4] = (_Float16)b.x; h[5] = (_Float16)b.y; h[6] = (_Float16)b.z; h[7] = (_Float16)b.w;
    xh8[t] = h;
}

// lazy dis: rsqrt(1 + sum_ew) straight from the packed word (float path:
// 44-bit fixed -> float loses ~2^-24 rel on deg -> ~1e-7 on dis; invisible
// at 0.1 tolerance).
__device__ __forceinline__ float dis_of(unsigned long long pk) {
    return rsqrtf(1.0f + (float)(pk & M44) * (1.0f / 4294967296.0f));
}

// k_gather_gemm (r11-PROVEN grid: 6250 blocks, 1 node per 16-lane group).
// r1 changes:
//  (a) H=true path gathers fp16 x (half4/lane = 128B/row) -> halves the
//      dominant L2-miss traffic (FETCH was 136MB).
//  (b) Bs staging swizzle s(k)=k -> s(k)=k>>2. Old scheme: within one
//      ds_write the 16 lanes' rows step by 4 so (gq+k)&15 hit only 4 chunk
//      positions -> 8-way bank conflict (the 7.2M SQ_LDS_BANK_CONFLICT).
//      New scheme: banks = 4*((gq+kc)&7)+oo -> exactly 2 lanes/bank (free).
//      Reads: chunk cg of row k=4kc+t now at position (cg+kc)&15.
template <bool H>
__global__ __launch_bounds__(256) void k_gather_gemm(const float* __restrict__ x,
                                                     const _Float16* __restrict__ xh,
                                                     const unsigned long long* __restrict__ packed,
                                                     const unsigned int* __restrict__ slots,
                                                     const int4* __restrict__ spill,
                                                     const int* __restrict__ spillCnt,
                                                     const float* __restrict__ W,
                                                     const float* __restrict__ bias,
                                                     float* __restrict__ out, int n) {
    __shared__ float Bs[D * D];        // 16 KB: Bs[k][o] = W[o][k], swizzled s(k)=k>>2
    __shared__ float Ast[16 * D];      // 4 KB: 16-row A tile, swizzled slots
    float4* Ast4 = (float4*)Ast;
    int tid = threadIdx.x;

    // Phase 0: stage W (issue first; overlaps the gather's global loads)
    const float4* W4 = (const float4*)W;
#pragma unroll
    for (int v = 0; v < 4; ++v) {
        int idx = tid + v * 256;       // 0..1023
        int o  = idx >> 4;             // out-ch 0..63
        int kc = idx & 15;
        float4 wv = W4[idx];
        int gq = o >> 2, oo = o & 3;
        int cpos = 4 * ((gq + kc) & 15) + oo;   // chunk-swizzle by kc: 2-way banks
        Bs[(4 * kc + 0) * 64 + cpos] = wv.x;
        Bs[(4 * kc + 1) * 64 + cpos] = wv.y;
        Bs[(4 * kc + 2) * 64 + cpos] = wv.z;
        Bs[(4 * kc + 3) * 64 + cpos] = wv.w;
    }

    // Phase 1: gather (one node per 16-lane group)
    int j   = tid & 15;                // k-chunk lane
    int grp = tid >> 4;                // 0..15
    int i0  = blockIdx.x * 16;
    int i   = i0 + grp;

    float4 acc = make_float4(0.f, 0.f, 0.f, 0.f);
    const float4* x4 = (const float4*)x;
    const half4*  xh4 = (const half4*)xh;
    if (i < n) {
        unsigned long long pk = packed[i];
        int rawc = (int)(pk >> 44);
        int c_n = rawc < K ? rawc : K;
        int s = i * K;
        for (int off = 0; off < c_n; off += 16) {
            int idx = off + j;
            unsigned int rec = 0u;
            float wj = 0.f;
            if (idx < c_n) {
                rec = slots[s + idx];
                wj = (float)(rec & 32767u) * (1.0f / 32768.0f) * dis_of(packed[rec >> 15]);
            }
            int mm = c_n - off; if (mm > 16) mm = 16;
#pragma unroll
            for (int t = 0; t < 16; ++t) {
                if (t < mm) {
                    int col = (int)((unsigned int)__shfl((int)rec, t, 16) >> 15);
                    float w = __shfl(wj, t, 16);
                    if constexpr (H) {
                        half4 hv = xh4[col * 16 + j];
                        acc.x += w * (float)hv[0]; acc.y += w * (float)hv[1];
                        acc.z += w * (float)hv[2]; acc.w += w * (float)hv[3];
                    } else {
                        float4 xv = x4[col * 16 + j];
                        acc.x += w * xv.x; acc.y += w * xv.y;
                        acc.z += w * xv.z; acc.w += w * xv.w;
                    }
                }
            }
        }
        if (rawc > K) {                // statistically ~10 edges in the graph
            int total = *spillCnt;
            if (total > SPILLCAP) total = SPILLCAP;
            for (int sp = 0; sp < total; ++sp) {
                int4 v = spill[sp];    // broadcast (same addr all lanes)
                if (v.x == i) {
                    float w = __int_as_float(v.z) * dis_of(packed[v.y]);
                    if constexpr (H) {
                        half4 hv = xh4[v.y * 16 + j];
                        acc.x += w * (float)hv[0]; acc.y += w * (float)hv[1];
                        acc.z += w * (float)hv[2]; acc.w += w * (float)hv[3];
                    } else {
                        float4 xv = x4[v.y * 16 + j];
                        acc.x += w * xv.x; acc.y += w * xv.y;
                        acc.z += w * xv.z; acc.w += w * xv.w;
                    }
                }
            }
        }
        float di = dis_of(pk);
        if constexpr (H) {
            half4 hi = xh4[i * 16 + j];
            acc.x = di * (di * (float)hi[0] + acc.x);
            acc.y = di * (di * (float)hi[1] + acc.y);
            acc.z = di * (di * (float)hi[2] + acc.z);
            acc.w = di * (di * (float)hi[3] + acc.w);
        } else {
            float4 xi = x4[i * 16 + j];
            acc.x = di * (di * xi.x + acc.x);
            acc.y = di * (di * xi.y + acc.y);
            acc.z = di * (di * xi.z + acc.z);
            acc.w = di * (di * xi.w + acc.w);
        }
    }
    Ast4[grp * 16 + ((j + (grp >> 2)) & 15)] = acc;   // swizzled slot
    __syncthreads();                   // covers Bs staging + Ast tile

    // Phase 2: 16x64 mini-GEMM (thread: row=grp', out-chs 4j..4j+3)
    int row = tid >> 4;
    int cg  = tid & 15;
    float4 oacc = ((const float4*)bias)[cg];
#pragma unroll 4
    for (int kc = 0; kc < 16; ++kc) {
        float4 a4 = Ast4[row * 16 + ((kc + (row >> 2)) & 15)];
        int cp = 4 * ((cg + kc) & 15);             // s(k)=kc read swizzle
        float4 b0 = *(const float4*)&Bs[(4 * kc + 0) * 64 + cp];
        float4 b1 = *(const float4*)&Bs[(4 * kc + 1) * 64 + cp];
        float4 b2 = *(const float4*)&Bs[(4 * kc + 2) * 64 + cp];
        float4 b3 = *(const float4*)&Bs[(4 * kc + 3) * 64 + cp];
        oacc.x += a4.x * b0.x + a4.y * b1.x + a4.z * b2.x + a4.w * b3.x;
        oacc.y += a4.x * b0.y + a4.y * b1.y + a4.z * b2.y + a4.w * b3.y;
        oacc.z += a4.x * b0.z + a4.y * b1.z + a4.z * b2.z + a4.w * b3.z;
        oacc.w += a4.x * b0.w + a4.y * b1.w + a4.z * b2.w + a4.w * b3.w;
    }
    int r = i0 + row;
    if (r < n) ((float4*)out)[r * 16 + cg] = oacc;
}

extern "C" void kernel_launch(void* const* d_in, const int* in_sizes, int n_in,
                              void* d_out, int out_size, void* d_ws, size_t ws_size,
                              hipStream_t stream) {
    const float* x    = (const float*)d_in[0];
    const int*   ei   = (const int*)d_in[1];   // [2*E] flat: rows then cols
    const float* ew   = (const float*)d_in[2];
    const float* W    = (const float*)d_in[3];
    const float* bias = (const float*)d_in[4];
    float* out = (float*)d_out;

    int n  = in_sizes[0] / D;   // 100000
    int nE = in_sizes[2];       // 1000000
    const int* rowi = ei;
    const int* coli = ei + nE;

    // workspace: packed | spillCnt | slots | spill | xh(fp16)
    char* w = (char*)d_ws;
    unsigned long long* packed = (unsigned long long*)w; w += (size_t)n * 8;
    int* spillCnt = (int*)w;                             w += 64;
    unsigned int* slots = (unsigned int*)w;              w += (size_t)n * K * 4;
    int4* spill = (int4*)w;                              w += (size_t)SPILLCAP * 16;
    _Float16* xh = (_Float16*)w;

    size_t need = (size_t)n * 8 + 64 + (size_t)n * K * 4 + (size_t)SPILLCAP * 16
                + (size_t)n * D * 2;
    bool useH = ws_size >= need;

    int gE = (nE + 255) / 256;
    int gT = (n + 15) / 16;     // 6250 blocks: 16 nodes/block, 1 node/group
    int nv = n * D / 8;         // 800000 half8s

    hipMemsetAsync(packed, 0, (size_t)n * 8 + 64, stream);   // packed + spillCnt
    if (useH)
        k_xhalf<<<(nv + 255) / 256, 256, 0, stream>>>((const float4*)x, (half8*)xh, nv);
    k_build<<<gE * 8, 256, 0, stream>>>(rowi, coli, ew, packed, slots, spill, spillCnt, nE);
    if (useH)
        k_gather_gemm<true><<<gT, 256, 0, stream>>>(x, xh, packed, slots, spill, spillCnt, W, bias, out, n);
    else
        k_gather_gemm<false><<<gT, 256, 0, stream>>>(x, xh, packed, slots, spill, spillCnt, W, bias, out, n);
}